// Round 1
// baseline (121.934 us; speedup 1.0000x reference)
//
#include <hip/hip_runtime.h>
#include <hip/hip_bf16.h>

#define Bn 512
#define Ln 2048
#define Tn 16
#define NCHUNK 8
#define CHUNK (Ln / NCHUNK)   // 256

typedef float f32x4 __attribute__((ext_vector_type(4)));
typedef short s16x4 __attribute__((ext_vector_type(4)));
typedef int   i32x2 __attribute__((ext_vector_type(2)));

#define L2E 1.4426950408889634f
#define LN2 0.6931471805599453f

#if __has_builtin(__builtin_amdgcn_mfma_f32_16x16x16bf16_1k)
#define HAVE_MFMA1K 1
#endif

__device__ __forceinline__ f32x4 mfma16(s16x4 a, s16x4 b, f32x4 c) {
#ifdef HAVE_MFMA1K
  return __builtin_amdgcn_mfma_f32_16x16x16bf16_1k(a, b, c, 0, 0, 0);
#else
  // fallback: raw ISA (cdna4_isa.md lists v_mfma_f32_16x16x16_bf16); conservative nops
  f32x4 d;
  asm volatile("v_mfma_f32_16x16x16_bf16 %0, %1, %2, %3\n\ts_nop 7\n\ts_nop 7"
               : "=v"(d) : "v"(a), "v"(b), "v"(c));
  return d;
#endif
}

__device__ __forceinline__ int cvtpk_bf16(float a, float b) {
  int r;
  asm("v_cvt_pk_bf16_f32 %0, %1, %2" : "=v"(r) : "v"(a), "v"(b));
  return r;
}

__device__ __forceinline__ float rl0(float x) {
  return __builtin_bit_cast(float, __builtin_amdgcn_readfirstlane(__builtin_bit_cast(int, x)));
}

// Kernel 1: per (batch, chunk) wave computes the chunk transfer matrix
//   T_chunk = prod_{t in chunk, mask} diag(exp(feat_t)) * E      (E = exp(trans))
// in scaled form: stored_T * 2^lnacc == true_T.  Also accumulates the gold-path
// partial score for the chunk via atomics.
__global__ __launch_bounds__(256, 2) void crf_chunk_kernel(
    const float* __restrict__ feats, const int* __restrict__ mask,
    const int* __restrict__ tgt, const float* __restrict__ trans,
    float* __restrict__ wsT, float* __restrict__ wsLn, float* __restrict__ wsGold)
{
  const int lane = threadIdx.x & 63;
  const int wid  = (blockIdx.x << 2) + (threadIdx.x >> 6);   // 0..4095
  const int b    = wid >> 3;
  const int c    = wid & (NCHUNK - 1);
  const int col  = lane & 15;
  const int r0   = (lane >> 4) << 2;

  // A fragment: A[m][k] = E[m][k], m = lane&15, k = r0..r0+3  (16x16x16 layout)
  s16x4 afrag;
  {
    const float4 tr = *(const float4*)(trans + col * 16 + r0);
    int p01 = cvtpk_bf16(__builtin_amdgcn_exp2f(tr.x * L2E), __builtin_amdgcn_exp2f(tr.y * L2E));
    int p23 = cvtpk_bf16(__builtin_amdgcn_exp2f(tr.z * L2E), __builtin_amdgcn_exp2f(tr.w * L2E));
    i32x2 t2; t2.x = p01; t2.y = p23;
    afrag = __builtin_bit_cast(s16x4, t2);
  }

  // B = T, init identity.  B[k = r0+i][n = col]; C/D layout matches B exactly.
  f32x4 qout;
  qout.x = (r0 + 0 == col) ? 1.f : 0.f;
  qout.y = (r0 + 1 == col) ? 1.f : 0.f;
  qout.z = (r0 + 2 == col) ? 1.f : 0.f;
  qout.w = (r0 + 3 == col) ? 1.f : 0.f;
  s16x4 bfrag;
  {
    i32x2 t2; t2.x = cvtpk_bf16(qout.x, qout.y); t2.y = cvtpk_bf16(qout.z, qout.w);
    bfrag = __builtin_bit_cast(s16x4, t2);
  }

  const int t0 = c * CHUNK;
  const size_t bL = (size_t)b * Ln;
  const float* fp = feats + (bL + t0) * Tn + r0;
  const int*   mp = mask + bL + t0;

  float lnacc = 0.f, pend = 0.f, s = 1.f;
  const f32x4 zero = {0.f, 0.f, 0.f, 0.f};

  int    mk = __builtin_amdgcn_readfirstlane(mp[0]);
  float4 ft = *(const float4*)fp;

  for (int t = 0; t < CHUNK; ++t) {
    if (!mk) break;                       // mask is a contiguous prefix
    // prefetch next step (clamped)
    const int tn = (t + 1 < CHUNK) ? t + 1 : t;
    const int    mkn = __builtin_amdgcn_readfirstlane(mp[tn]);
    const float4 ftn = *(const float4*)(fp + (size_t)tn * Tn);

    // row scales: F_i = exp(feat[r0+i]) * s   (s = running normalizer, applied late)
    const float F0 = __builtin_amdgcn_exp2f(ft.x * L2E) * s;
    const float F1 = __builtin_amdgcn_exp2f(ft.y * L2E) * s;
    const float F2 = __builtin_amdgcn_exp2f(ft.z * L2E) * s;
    const float F3 = __builtin_amdgcn_exp2f(ft.w * L2E) * s;

    const f32x4 p = mfma16(afrag, bfrag, zero);   // E * T
    f32x4 q;
    q.x = p.x * F0; q.y = p.y * F1; q.z = p.z * F2; q.w = p.w * F3;

    // repack as next B fragment (C layout == B layout)
    i32x2 t2; t2.x = cvtpk_bf16(q.x, q.y); t2.y = cvtpk_bf16(q.z, q.w);
    bfrag = __builtin_bit_cast(s16x4, t2);
    qout = q;

    // normalization bookkeeping, off the MFMA critical path:
    // c0 = T'[0][0]; next step scaled by 1/c0; lnacc counts only APPLIED scales.
    const float c0 = rl0(q.x);
    lnacc += pend;
    pend = __builtin_amdgcn_logf(c0);     // log2
    s = __builtin_amdgcn_rcpf(c0);

    ft = ftn; mk = mkn;
  }

  *(f32x4*)(wsT + ((size_t)wid * 64 + lane) * 4) = qout;
  if (lane == 0) wsLn[wid] = lnacc;

  // ---- gold-path partial for this chunk (feats region is L2-hot) ----
  float gs = 0.f;
  for (int k2 = 0; k2 < CHUNK / 64; ++k2) {
    const int t = t0 + k2 * 64 + lane;
    if (mask[bL + t]) {
      const int cur = tgt[bL + t];
      const int prv = (t == 0) ? 0 : tgt[bL + t - 1];   // START_TAG = 0
      gs += trans[cur * 16 + prv] + feats[(bL + t) * 16 + cur];
    }
  }
  for (int m = 1; m < 64; m <<= 1) gs += __shfl_xor(gs, m);
  if (lane == 0) atomicAdd(wsGold + b, gs);
}

// Kernel 2: per-batch wave combines the 8 chunk matrices against u0 = e_START,
// terminal logsumexp with trans[STOP] row, subtracts gold, reduces to scalar.
__global__ __launch_bounds__(256) void crf_combine_kernel(
    const int* __restrict__ mask, const int* __restrict__ tgt,
    const float* __restrict__ trans, const float* __restrict__ wsT,
    const float* __restrict__ wsLn, const float* __restrict__ wsGold,
    float* __restrict__ out)
{
  const int lane = threadIdx.x & 63;
  const int b    = (blockIdx.x << 2) + (threadIdx.x >> 6);
  const int col  = lane & 15;

  float u    = (col == 0) ? 1.f : 0.f;   // exp(fv_init): e_START (others underflow to 0)
  float Lacc = 0.f;                      // log2 units

  for (int c = 0; c < NCHUNK; ++c) {
    const float4 tf = *(const float4*)(wsT + (((size_t)b * NCHUNK + c) * 64 + lane) * 4);
    // lane holds T[r0+i][col]; partial = T[.][col] * u[col]
    float p0 = tf.x * u, p1 = tf.y * u, p2 = tf.z * u, p3 = tf.w * u;
    for (int m = 1; m < 16; m <<= 1) {
      p0 += __shfl_xor(p0, m); p1 += __shfl_xor(p1, m);
      p2 += __shfl_xor(p2, m); p3 += __shfl_xor(p3, m);
    }
    // redistribute: lane wants u'[col]; group (col>>2) holds it as elem (col&3)
    const float pre = (lane & 2) ? ((lane & 1) ? p3 : p2) : ((lane & 1) ? p1 : p0);
    const int srcl = ((lane & 12) << 2) + (lane & 3);
    float un = __shfl(pre, srcl);
    const float c0 = rl0(un);            // u'[0] > 0 always
    Lacc += __builtin_amdgcn_logf(c0) + wsLn[(size_t)b * NCHUNK + c];
    u = un * __builtin_amdgcn_rcpf(c0);
  }

  // terminal: fwd = ln( sum_n u_n * exp(trans[STOP][n]) ) + LN2*Lacc
  float v = u * __builtin_amdgcn_exp2f(trans[16 + col] * L2E);   // STOP_TAG = 1
  for (int m = 1; m < 16; m <<= 1) v += __shfl_xor(v, m);
  const float fwd = LN2 * (Lacc + __builtin_amdgcn_logf(v));

  // length = sum(mask[b,:])
  const size_t bL = (size_t)b * Ln;
  int cnt = 0;
  for (int i = lane; i < Ln; i += 64) cnt += mask[bL + i];
  for (int m = 1; m < 64; m <<= 1) cnt += __shfl_xor(cnt, m);

  if (lane == 0) {
    const int last = tgt[bL + cnt - 1];
    const float gold = wsGold[b] + trans[16 + last];
    atomicAdd(out, (fwd - gold) * (1.f / 512.f));
  }
}

extern "C" void kernel_launch(void* const* d_in, const int* in_sizes, int n_in,
                              void* d_out, int out_size, void* d_ws, size_t ws_size,
                              hipStream_t stream) {
  const float* feats = (const float*)d_in[0];
  const int*   mask  = (const int*)d_in[1];
  const int*   tgt   = (const int*)d_in[2];
  const float* trans = (const float*)d_in[3];
  float* out = (float*)d_out;

  char* ws = (char*)d_ws;
  float* wsGold = (float*)ws;                      // 512 * 4B
  float* wsLn   = (float*)(ws + 2048);             // 4096 * 4B
  float* wsT    = (float*)(ws + 2048 + 16384);     // 4096 * 256 * 4B = 4 MiB

  hipMemsetAsync(d_out, 0, sizeof(float), stream);
  hipMemsetAsync(wsGold, 0, Bn * sizeof(float), stream);

  crf_chunk_kernel<<<Bn * NCHUNK / 4, 256, 0, stream>>>(feats, mask, tgt, trans,
                                                        wsT, wsLn, wsGold);
  crf_combine_kernel<<<Bn / 4, 256, 0, stream>>>(mask, tgt, trans, wsT, wsLn, wsGold, out);
}

// Round 5
// 102.806 us; speedup vs baseline: 1.1861x; 1.1861x over previous
//
#include <hip/hip_runtime.h>
#include <hip/hip_bf16.h>

#define Bn 512
#define Ln 2048
#define Tn 16
#define NC 8
#define CH (Ln / NC)   // 256

typedef float f32x4 __attribute__((ext_vector_type(4)));
typedef short s16x4 __attribute__((ext_vector_type(4)));
typedef int   i32x2 __attribute__((ext_vector_type(2)));

#define L2E 1.4426950408889634f
#define LN2 0.6931471805599453f

#if __has_builtin(__builtin_amdgcn_mfma_f32_16x16x16bf16_1k)
#define HAVE_MFMA1K 1
#endif

__device__ __forceinline__ f32x4 mfma16(s16x4 a, s16x4 b, f32x4 c) {
#ifdef HAVE_MFMA1K
  return __builtin_amdgcn_mfma_f32_16x16x16bf16_1k(a, b, c, 0, 0, 0);
#else
  f32x4 d;
  asm volatile("v_mfma_f32_16x16x16_bf16 %0, %1, %2, %3\n\ts_nop 7\n\ts_nop 7"
               : "=&v"(d) : "v"(a), "v"(b), "v"(c));
  return d;
#endif
}

__device__ __forceinline__ int cvtpk_bf16(float a, float b) {
  int r;
  asm("v_cvt_pk_bf16_f32 %0, %1, %2" : "=v"(r) : "v"(a), "v"(b));
  return r;
}

__device__ __forceinline__ s16x4 pack_bf16(f32x4 q) {
  i32x2 t2; t2.x = cvtpk_bf16(q.x, q.y); t2.y = cvtpk_bf16(q.z, q.w);
  return __builtin_bit_cast(s16x4, t2);
}

__device__ __forceinline__ float rl0(float x) {
  return __builtin_bit_cast(float, __builtin_amdgcn_readfirstlane(__builtin_bit_cast(int, x)));
}

// Predicated scan step (R1-proven numerics, per-step T[0][0] renorm).
// stored_T * 2^lnacc == true_T; `pend` is the not-yet-applied last scale.
#define PSTEP(fr, tt)                                                         \
  {                                                                           \
    const bool live = (tt) < nsteps;                                          \
    const float F0 = __builtin_amdgcn_exp2f(fr.x * L2E) * s;                  \
    const float F1 = __builtin_amdgcn_exp2f(fr.y * L2E) * s;                  \
    const float F2 = __builtin_amdgcn_exp2f(fr.z * L2E) * s;                  \
    const float F3 = __builtin_amdgcn_exp2f(fr.w * L2E) * s;                  \
    const f32x4 p = mfma16(afrag, bfrag, zero);                               \
    f32x4 qn;                                                                 \
    qn.x = p.x * F0; qn.y = p.y * F1; qn.z = p.z * F2; qn.w = p.w * F3;       \
    const float c0n = fmaxf(rl0(qn.x), 1e-30f);                               \
    if (live) {                                                               \
      q = qn; bfrag = pack_bf16(qn);                                          \
      lnacc += pend;                                                          \
      pend = __builtin_amdgcn_logf(c0n); /* log2 */                           \
      s = __builtin_amdgcn_rcpf(c0n);                                         \
    }                                                                         \
  }

#define LOADQ(dst, ii)                                                        \
  dst = *(const float4*)(fp + (size_t)((ii) < CH ? (ii) : CH - 1) * Tn);

// Kernel 1: per (batch, chunk) wave computes the chunk transfer matrix
//   T_chunk = prod_t diag(exp(feat_t)) * E,  E = exp(trans)
// Feats read directly from global (R1 pattern) with a 16-step register
// software pipeline (two named octs; next oct's loads issued a phase ahead).
__global__ __launch_bounds__(256, 2) void crf_chunk(
    const float* __restrict__ feats, const int* __restrict__ mask,
    const int* __restrict__ tgt, const float* __restrict__ trans,
    float* __restrict__ wsT, float* __restrict__ wsLn, float* __restrict__ wsGold)
{
  const int lane = threadIdx.x & 63;
  const int widx = threadIdx.x >> 6;
  const int gwid = (blockIdx.x << 2) + widx;
  const int b = gwid / NC;
  const int c = gwid & (NC - 1);
  const int col = lane & 15;
  const int r0 = (lane >> 4) << 2;

  // A fragment: A[m=col][k=r0+i] = exp(trans[col][r0+i])
  s16x4 afrag;
  {
    const float4 tr = *(const float4*)(trans + col * 16 + r0);
    f32x4 e;
    e.x = __builtin_amdgcn_exp2f(tr.x * L2E);
    e.y = __builtin_amdgcn_exp2f(tr.y * L2E);
    e.z = __builtin_amdgcn_exp2f(tr.z * L2E);
    e.w = __builtin_amdgcn_exp2f(tr.w * L2E);
    afrag = pack_bf16(e);
  }

  const size_t bL = (size_t)b * Ln;
  const int t0 = c * CH;

  // nsteps = number of mask=1 steps in this chunk (mask is a prefix):
  // one int4 per lane covers all CH=256 entries.
  int nsteps;
  {
    const int4 mv = *(const int4*)(mask + bL + t0 + lane * 4);
    int cnt = mv.x + mv.y + mv.z + mv.w;
    for (int m = 1; m < 64; m <<= 1) cnt += __shfl_xor(cnt, m);
    nsteps = cnt;
  }

  f32x4 q;  // B = T (identity init). B[k=r0+i][n=col]; C/D layout == B layout.
  q.x = (r0 + 0 == col) ? 1.f : 0.f;
  q.y = (r0 + 1 == col) ? 1.f : 0.f;
  q.z = (r0 + 2 == col) ? 1.f : 0.f;
  q.w = (r0 + 3 == col) ? 1.f : 0.f;
  s16x4 bfrag = pack_bf16(q);
  float lnacc = 0.f;
  const f32x4 zero = {0.f, 0.f, 0.f, 0.f};

  if (nsteps > 0) {
    const float* fp = feats + (bL + (size_t)t0) * Tn + r0;
    float s = 1.f, pend = 0.f;

    float4 a0, a1, a2, a3, a4, a5, a6, a7;
    float4 b0, b1, b2, b3, b4, b5, b6, b7;
    LOADQ(a0, 0) LOADQ(a1, 1) LOADQ(a2, 2) LOADQ(a3, 3)
    LOADQ(a4, 4) LOADQ(a5, 5) LOADQ(a6, 6) LOADQ(a7, 7)

    const int niter = (nsteps + 15) >> 4;   // 16 steps per iteration
    for (int it = 0; it < niter; ++it) {
      const int base = it << 4;
      // phase A: prefetch oct B, compute steps base..base+7 from oct A
      LOADQ(b0, base + 8)  LOADQ(b1, base + 9)  LOADQ(b2, base + 10) LOADQ(b3, base + 11)
      LOADQ(b4, base + 12) LOADQ(b5, base + 13) LOADQ(b6, base + 14) LOADQ(b7, base + 15)
      PSTEP(a0, base + 0) PSTEP(a1, base + 1) PSTEP(a2, base + 2) PSTEP(a3, base + 3)
      PSTEP(a4, base + 4) PSTEP(a5, base + 5) PSTEP(a6, base + 6) PSTEP(a7, base + 7)
      // phase B: prefetch next oct A, compute steps base+8..base+15 from oct B
      LOADQ(a0, base + 16) LOADQ(a1, base + 17) LOADQ(a2, base + 18) LOADQ(a3, base + 19)
      LOADQ(a4, base + 20) LOADQ(a5, base + 21) LOADQ(a6, base + 22) LOADQ(a7, base + 23)
      PSTEP(b0, base + 8)  PSTEP(b1, base + 9)  PSTEP(b2, base + 10) PSTEP(b3, base + 11)
      PSTEP(b4, base + 12) PSTEP(b5, base + 13) PSTEP(b6, base + 14) PSTEP(b7, base + 15)
    }
  }

  *(f32x4*)(wsT + ((size_t)gwid * 64 + lane) * 4) = q;
  if (lane == 0) wsLn[gwid] = lnacc;

  // ---- gold-path partial for this chunk (R1-verbatim, mask-based) ----
  float gs = 0.f;
#pragma unroll
  for (int k2 = 0; k2 < CH / 64; ++k2) {
    const int t = t0 + k2 * 64 + lane;
    if (mask[bL + t]) {
      const int cur = tgt[bL + t];
      const int prv = (t == 0) ? 0 : tgt[bL + t - 1];  // START_TAG = 0
      gs += trans[cur * 16 + prv] + feats[(bL + t) * 16 + cur];
    }
  }
  for (int m = 1; m < 64; m <<= 1) gs += __shfl_xor(gs, m);
  if (lane == 0) atomicAdd(wsGold + b, gs);
}

// Kernel 2: per-batch wave combines chunk matrices against u0 = e_START,
// terminal logsumexp with trans[STOP] row, subtracts gold, reduces to scalar.
__global__ __launch_bounds__(256) void crf_combine(
    const int* __restrict__ mask, const int* __restrict__ tgt,
    const float* __restrict__ trans, const float* __restrict__ wsT,
    const float* __restrict__ wsLn, const float* __restrict__ wsGold,
    float* __restrict__ out)
{
  const int lane = threadIdx.x & 63;
  const int b = (blockIdx.x << 2) + (threadIdx.x >> 6);
  const int col = lane & 15;

  float u = (col == 0) ? 1.f : 0.f;  // exp(fv_init) = e_START
  float Lacc = 0.f;                  // log2 units

  for (int c = 0; c < NC; ++c) {
    const float4 tf = *(const float4*)(wsT + (((size_t)b * NC + c) * 64 + lane) * 4);
    float p0 = tf.x * u, p1 = tf.y * u, p2 = tf.z * u, p3 = tf.w * u;
    for (int m = 1; m < 16; m <<= 1) {
      p0 += __shfl_xor(p0, m); p1 += __shfl_xor(p1, m);
      p2 += __shfl_xor(p2, m); p3 += __shfl_xor(p3, m);
    }
    const float pre = (lane & 2) ? ((lane & 1) ? p3 : p2) : ((lane & 1) ? p1 : p0);
    const int srcl = ((lane & 12) << 2) + (lane & 3);
    float un = __shfl(pre, srcl);
    const float c0 = fmaxf(rl0(un), 1e-30f);
    Lacc += __builtin_amdgcn_logf(c0) + wsLn[(size_t)b * NC + c];
    u = un * __builtin_amdgcn_rcpf(c0);
  }

  float v = u * __builtin_amdgcn_exp2f(trans[16 + col] * L2E);  // STOP_TAG = 1
  for (int m = 1; m < 16; m <<= 1) v += __shfl_xor(v, m);
  v = fmaxf(v, 1e-30f);
  const float fwd = LN2 * (Lacc + __builtin_amdgcn_logf(v));

  // length = sum(mask[b,:])  (R1-verbatim)
  const size_t bL = (size_t)b * Ln;
  int cnt = 0;
  for (int i = lane; i < Ln; i += 64) cnt += mask[bL + i];
  for (int m = 1; m < 64; m <<= 1) cnt += __shfl_xor(cnt, m);

  if (lane == 0) {
    const int last = tgt[bL + cnt - 1];
    const float gold = wsGold[b] + trans[16 + last];
    atomicAdd(out, (fwd - gold) * (1.f / 512.f));
  }
}

extern "C" void kernel_launch(void* const* d_in, const int* in_sizes, int n_in,
                              void* d_out, int out_size, void* d_ws, size_t ws_size,
                              hipStream_t stream) {
  const float* feats = (const float*)d_in[0];
  const int* mask = (const int*)d_in[1];
  const int* tgt = (const int*)d_in[2];
  const float* trans = (const float*)d_in[3];
  float* out = (float*)d_out;

  char* ws = (char*)d_ws;
  float* wsGold = (float*)ws;                      // 512 * 4B
  float* wsLn   = (float*)(ws + 2048);             // NC*512 * 4B = 16KB
  float* wsT    = (float*)(ws + 2048 + 16384);     // NC*512*256*4 = 4MB

  hipMemsetAsync(d_out, 0, sizeof(float), stream);
  hipMemsetAsync(wsGold, 0, Bn * sizeof(float), stream);

  crf_chunk<<<Bn * NC / 4, 256, 0, stream>>>(feats, mask, tgt, trans, wsT, wsLn, wsGold);
  crf_combine<<<Bn / 4, 256, 0, stream>>>(mask, tgt, trans, wsT, wsLn, wsGold, out);
}

// Round 6
// 87.911 us; speedup vs baseline: 1.3870x; 1.1694x over previous
//
#include <hip/hip_runtime.h>
#include <hip/hip_bf16.h>

#define Bn 512
#define Ln 2048
#define Tn 16

typedef float f32x4 __attribute__((ext_vector_type(4)));
typedef short s16x4 __attribute__((ext_vector_type(4)));
typedef int   i32x2 __attribute__((ext_vector_type(2)));

#define L2E 1.4426950408889634f
#define LN2 0.6931471805599453f

#if __has_builtin(__builtin_amdgcn_mfma_f32_16x16x16bf16_1k)
#define HAVE_MFMA1K 1
#endif

__device__ __forceinline__ f32x4 mfma16(s16x4 a, s16x4 b, f32x4 c) {
#ifdef HAVE_MFMA1K
  return __builtin_amdgcn_mfma_f32_16x16x16bf16_1k(a, b, c, 0, 0, 0);
#else
  f32x4 d;
  asm volatile("v_mfma_f32_16x16x16_bf16 %0, %1, %2, %3\n\ts_nop 7\n\ts_nop 7"
               : "=&v"(d) : "v"(a), "v"(b), "v"(c));
  return d;
#endif
}

__device__ __forceinline__ int cvtpk_bf16(float a, float b) {
  int r;
  asm("v_cvt_pk_bf16_f32 %0, %1, %2" : "=v"(r) : "v"(a), "v"(b));
  return r;
}

__device__ __forceinline__ s16x4 pack_bf16(f32x4 q) {
  i32x2 t2; t2.x = cvtpk_bf16(q.x, q.y); t2.y = cvtpk_bf16(q.z, q.w);
  return __builtin_bit_cast(s16x4, t2);
}

__device__ __forceinline__ float rl0(float x) {
  return __builtin_bit_cast(float, __builtin_amdgcn_readfirstlane(__builtin_bit_cast(int, x)));
}

// Unpredicated scan step. Applied scale is exactly 2^-pend (fma-folded into
// exp2), so stored_T * 2^lnacc == true_T exactly-consistently.
// Invariant: after step k commits, lnacc = sum_{j<k} pend_j.
#define STEPNP(fr)                                                            \
  {                                                                           \
    const float F0 = __builtin_amdgcn_exp2f(__builtin_fmaf(fr.x, L2E, mpend));\
    const float F1 = __builtin_amdgcn_exp2f(__builtin_fmaf(fr.y, L2E, mpend));\
    const float F2 = __builtin_amdgcn_exp2f(__builtin_fmaf(fr.z, L2E, mpend));\
    const float F3 = __builtin_amdgcn_exp2f(__builtin_fmaf(fr.w, L2E, mpend));\
    const f32x4 p = mfma16(afrag, bfrag, zero);                               \
    q.x = p.x * F0; q.y = p.y * F1; q.z = p.z * F2; q.w = p.w * F3;           \
    bfrag = pack_bf16(q);                                                     \
    lnacc += pend;                                                            \
    const float c0 = fmaxf(rl0(q.x), 1e-30f);                                 \
    pend = __builtin_amdgcn_logf(c0); /* log2 */                              \
    mpend = -pend;                                                            \
  }

// Predicated variant for the tail (< 8 live steps remain).
#define PSTEP(fr, tt)                                                         \
  {                                                                           \
    const bool live = (tt) < nsteps;                                          \
    const float F0 = __builtin_amdgcn_exp2f(__builtin_fmaf(fr.x, L2E, mpend));\
    const float F1 = __builtin_amdgcn_exp2f(__builtin_fmaf(fr.y, L2E, mpend));\
    const float F2 = __builtin_amdgcn_exp2f(__builtin_fmaf(fr.z, L2E, mpend));\
    const float F3 = __builtin_amdgcn_exp2f(__builtin_fmaf(fr.w, L2E, mpend));\
    const f32x4 p = mfma16(afrag, bfrag, zero);                               \
    f32x4 qn;                                                                 \
    qn.x = p.x * F0; qn.y = p.y * F1; qn.z = p.z * F2; qn.w = p.w * F3;       \
    const float c0n = fmaxf(rl0(qn.x), 1e-30f);                               \
    if (live) {                                                               \
      q = qn; bfrag = pack_bf16(qn);                                          \
      lnacc += pend;                                                          \
      pend = __builtin_amdgcn_logf(c0n);                                      \
      mpend = -pend;                                                          \
    }                                                                         \
  }

#define LOADQ(dst, ii)                                                        \
  dst = *(const float4*)(fp + (size_t)((ii) < CHrt ? (ii) : CHrt - 1) * Tn);

// Kernel 1: per (batch, chunk) wave computes the chunk transfer matrix
//   T_chunk = prod_t diag(exp(feat_t)) * E,  E = exp(trans)
// Feats read directly from global with an 8-step register software pipeline.
__global__ __launch_bounds__(256, 8) void crf_chunk(
    const float* __restrict__ feats, const int* __restrict__ mask,
    const int* __restrict__ tgt, const float* __restrict__ trans,
    float* __restrict__ wsT, float* __restrict__ wsLn, float* __restrict__ wsGold,
    int ncs)
{
  const int lane = threadIdx.x & 63;
  const int gwid = (blockIdx.x << 2) + (threadIdx.x >> 6);
  const int b = gwid >> ncs;
  const int c = gwid & ((1 << ncs) - 1);
  const int CHrt = Ln >> ncs;
  const int col = lane & 15;
  const int r0 = (lane >> 4) << 2;

  // A fragment: A[m=col][k=r0+i] = exp(trans[col][r0+i])
  s16x4 afrag;
  {
    const float4 tr = *(const float4*)(trans + col * 16 + r0);
    f32x4 e;
    e.x = __builtin_amdgcn_exp2f(tr.x * L2E);
    e.y = __builtin_amdgcn_exp2f(tr.y * L2E);
    e.z = __builtin_amdgcn_exp2f(tr.z * L2E);
    e.w = __builtin_amdgcn_exp2f(tr.w * L2E);
    afrag = pack_bf16(e);
  }

  const size_t bL = (size_t)b * Ln;
  const int t0 = c * CHrt;

  // nsteps = count of mask=1 in this chunk (mask is a contiguous prefix).
  int nsteps;
  {
    int cnt = 0;
    if (lane * 4 < CHrt) {
      const int4 mv = *(const int4*)(mask + bL + t0 + lane * 4);
      cnt = mv.x + mv.y + mv.z + mv.w;
    }
    for (int m = 1; m < 64; m <<= 1) cnt += __shfl_xor(cnt, m);
    nsteps = cnt;
  }

  f32x4 q;  // B = T (identity init). B[k=r0+i][n=col]; C/D layout == B layout.
  q.x = (r0 + 0 == col) ? 1.f : 0.f;
  q.y = (r0 + 1 == col) ? 1.f : 0.f;
  q.z = (r0 + 2 == col) ? 1.f : 0.f;
  q.w = (r0 + 3 == col) ? 1.f : 0.f;
  s16x4 bfrag = pack_bf16(q);
  float lnacc = 0.f;
  const f32x4 zero = {0.f, 0.f, 0.f, 0.f};

  if (nsteps > 0) {
    const float* fp = feats + (bL + (size_t)t0) * Tn + r0;
    float pend = 0.f, mpend = 0.f;

    float4 a0, a1, a2, a3, b0, b1, b2, b3;
    LOADQ(a0, 0) LOADQ(a1, 1) LOADQ(a2, 2) LOADQ(a3, 3)

    const int full8 = nsteps >> 3;
    const int tail = nsteps & 7;
    for (int it = 0; it < full8; ++it) {
      const int base = it << 3;
      LOADQ(b0, base + 4) LOADQ(b1, base + 5) LOADQ(b2, base + 6) LOADQ(b3, base + 7)
      STEPNP(a0) STEPNP(a1) STEPNP(a2) STEPNP(a3)
      LOADQ(a0, base + 8) LOADQ(a1, base + 9) LOADQ(a2, base + 10) LOADQ(a3, base + 11)
      STEPNP(b0) STEPNP(b1) STEPNP(b2) STEPNP(b3)
    }
    if (tail) {
      const int base = full8 << 3;
      LOADQ(b0, base + 4) LOADQ(b1, base + 5) LOADQ(b2, base + 6) LOADQ(b3, base + 7)
      PSTEP(a0, base + 0) PSTEP(a1, base + 1) PSTEP(a2, base + 2) PSTEP(a3, base + 3)
      PSTEP(b0, base + 4) PSTEP(b1, base + 5) PSTEP(b2, base + 6) PSTEP(b3, base + 7)
    }
  }

  *(f32x4*)(wsT + ((size_t)gwid * 64 + lane) * 4) = q;
  if (lane == 0) wsLn[gwid] = lnacc;

  // ---- gold-path partial for this chunk (mask-based, R5-verbatim) ----
  float gs = 0.f;
  const int ngold = CHrt >> 6;
  for (int k2 = 0; k2 < ngold; ++k2) {
    const int t = t0 + k2 * 64 + lane;
    if (mask[bL + t]) {
      const int cur = tgt[bL + t];
      const int prv = (t == 0) ? 0 : tgt[bL + t - 1];  // START_TAG = 0
      gs += trans[cur * 16 + prv] + feats[(bL + t) * 16 + cur];
    }
  }
  for (int m = 1; m < 64; m <<= 1) gs += __shfl_xor(gs, m);
  if (lane == 0) atomicAdd(wsGold + b, gs);
}

// Kernel 2: per-batch wave combines chunk matrices against u0 = e_START,
// terminal logsumexp with trans[STOP] row, subtracts gold, reduces to scalar.
__global__ __launch_bounds__(256) void crf_combine(
    const int* __restrict__ mask, const int* __restrict__ tgt,
    const float* __restrict__ trans, const float* __restrict__ wsT,
    const float* __restrict__ wsLn, const float* __restrict__ wsGold,
    float* __restrict__ out, int ncs)
{
  const int lane = threadIdx.x & 63;
  const int b = (blockIdx.x << 2) + (threadIdx.x >> 6);
  const int col = lane & 15;
  const int NCrt = 1 << ncs;

  float u = (col == 0) ? 1.f : 0.f;  // exp(fv_init) = e_START
  float Lacc = 0.f;                  // log2 units

  for (int c = 0; c < NCrt; ++c) {
    const float4 tf = *(const float4*)(wsT + (((size_t)(b << ncs) + c) * 64 + lane) * 4);
    float p0 = tf.x * u, p1 = tf.y * u, p2 = tf.z * u, p3 = tf.w * u;
    for (int m = 1; m < 16; m <<= 1) {
      p0 += __shfl_xor(p0, m); p1 += __shfl_xor(p1, m);
      p2 += __shfl_xor(p2, m); p3 += __shfl_xor(p3, m);
    }
    const float pre = (lane & 2) ? ((lane & 1) ? p3 : p2) : ((lane & 1) ? p1 : p0);
    const int srcl = ((lane & 12) << 2) + (lane & 3);
    float un = __shfl(pre, srcl);
    const float c0 = fmaxf(rl0(un), 1e-30f);
    Lacc += __builtin_amdgcn_logf(c0) + wsLn[(size_t)(b << ncs) + c];
    u = un * __builtin_amdgcn_rcpf(c0);
  }

  float v = u * __builtin_amdgcn_exp2f(trans[16 + col] * L2E);  // STOP_TAG = 1
  for (int m = 1; m < 16; m <<= 1) v += __shfl_xor(v, m);
  v = fmaxf(v, 1e-30f);
  const float fwd = LN2 * (Lacc + __builtin_amdgcn_logf(v));

  // length = sum(mask[b,:])
  const size_t bL = (size_t)b * Ln;
  int cnt = 0;
  for (int i = lane; i < Ln; i += 64) cnt += mask[bL + i];
  for (int m = 1; m < 64; m <<= 1) cnt += __shfl_xor(cnt, m);

  if (lane == 0) {
    const int last = tgt[bL + cnt - 1];
    const float gold = wsGold[b] + trans[16 + last];
    atomicAdd(out, (fwd - gold) * (1.f / 512.f));
  }
}

extern "C" void kernel_launch(void* const* d_in, const int* in_sizes, int n_in,
                              void* d_out, int out_size, void* d_ws, size_t ws_size,
                              hipStream_t stream) {
  const float* feats = (const float*)d_in[0];
  const int* mask = (const int*)d_in[1];
  const int* tgt = (const int*)d_in[2];
  const float* trans = (const float*)d_in[3];
  float* out = (float*)d_out;

  char* ws = (char*)d_ws;
  float* wsGold = (float*)ws;                      // 512 * 4B
  float* wsLn   = (float*)(ws + 2048);             // up to 16*512 * 4B = 32KB
  float* wsT    = (float*)(ws + 2048 + 32768);     // up to 16*512*256*4 = 8MB

  // NC = 16 if workspace allows (8.4 MB), else 8 (4.2 MB).
  const size_t need16 = 2048 + 32768 + (size_t)16 * Bn * 256 * 4;
  const int ncs = (ws_size >= need16) ? 4 : 3;
  const int nwaves = Bn << ncs;

  hipMemsetAsync(d_out, 0, sizeof(float), stream);
  hipMemsetAsync(wsGold, 0, Bn * sizeof(float), stream);

  crf_chunk<<<nwaves / 4, 256, 0, stream>>>(feats, mask, tgt, trans, wsT, wsLn, wsGold, ncs);
  crf_combine<<<Bn / 4, 256, 0, stream>>>(mask, tgt, trans, wsT, wsLn, wsGold, out, ncs);
}

// Round 7
// 73.089 us; speedup vs baseline: 1.6683x; 1.2028x over previous
//
#include <hip/hip_runtime.h>
#include <hip/hip_bf16.h>

#define Bn 512
#define Ln 2048
#define Tn 16

typedef float f32x4 __attribute__((ext_vector_type(4)));
typedef short s16x4 __attribute__((ext_vector_type(4)));
typedef int   i32x2 __attribute__((ext_vector_type(2)));

#define L2E 1.4426950408889634f
#define LN2 0.6931471805599453f

#if __has_builtin(__builtin_amdgcn_mfma_f32_16x16x16bf16_1k)
#define HAVE_MFMA1K 1
#endif

__device__ __forceinline__ f32x4 mfma16(s16x4 a, s16x4 b, f32x4 c) {
#ifdef HAVE_MFMA1K
  return __builtin_amdgcn_mfma_f32_16x16x16bf16_1k(a, b, c, 0, 0, 0);
#else
  f32x4 d;
  asm volatile("v_mfma_f32_16x16x16_bf16 %0, %1, %2, %3\n\ts_nop 7\n\ts_nop 7"
               : "=&v"(d) : "v"(a), "v"(b), "v"(c));
  return d;
#endif
}

__device__ __forceinline__ int cvtpk_bf16(float a, float b) {
  int r;
  asm("v_cvt_pk_bf16_f32 %0, %1, %2" : "=v"(r) : "v"(a), "v"(b));
  return r;
}

__device__ __forceinline__ s16x4 pack_bf16(f32x4 q) {
  i32x2 t2; t2.x = cvtpk_bf16(q.x, q.y); t2.y = cvtpk_bf16(q.z, q.w);
  return __builtin_bit_cast(s16x4, t2);
}

__device__ __forceinline__ float rl0(float x) {
  return __builtin_bit_cast(float, __builtin_amdgcn_readfirstlane(__builtin_bit_cast(int, x)));
}

// Kernel 0: lengths[b] = sum(mask[b,:])  (mask is a contiguous prefix)
__global__ __launch_bounds__(256) void len_kernel(const int* __restrict__ mask,
                                                  int* __restrict__ wsLen) {
  const int lane = threadIdx.x & 63;
  const int b = (blockIdx.x << 2) + (threadIdx.x >> 6);
  const int4* mp = (const int4*)(mask + (size_t)b * Ln);
  int cnt = 0;
#pragma unroll
  for (int i = 0; i < Ln / 4 / 64; ++i) {
    int4 v = mp[i * 64 + lane];
    cnt += v.x + v.y + v.z + v.w;
  }
  for (int m = 1; m < 64; m <<= 1) cnt += __shfl_xor(cnt, m);
  if (lane == 0) wsLen[b] = cnt;
}

// One scan step. exCur holds, per lane (= j*16+row), exp(feat[tb+j][row]).
// The 4 F values this lane needs (rows r0..r0+3 at step j) come via shfl
// (DS pipe). Renorm every 2 steps (RENORM), applied deferred (APPLY).
// Invariant: stored_T * 2^lnacc == true_T; lnacc holds only APPLIED pends.
#define GBODY(j, APPLY, RENORM)                                               \
  {                                                                           \
    float F0 = __shfl(exCur, ((j) << 4) + r0 + 0);                            \
    float F1 = __shfl(exCur, ((j) << 4) + r0 + 1);                            \
    float F2 = __shfl(exCur, ((j) << 4) + r0 + 2);                            \
    float F3 = __shfl(exCur, ((j) << 4) + r0 + 3);                            \
    const f32x4 p = mfma16(afrag, bfrag, zero);                               \
    if (APPLY) { F0 *= s; F1 *= s; F2 *= s; F3 *= s; lnacc += pend; }         \
    q.x = p.x * F0; q.y = p.y * F1; q.z = p.z * F2; q.w = p.w * F3;           \
    bfrag = pack_bf16(q);                                                     \
    if (RENORM) {                                                             \
      const float c0 = fmaxf(rl0(q.x), 1e-30f);                               \
      pend = __builtin_amdgcn_logf(c0); /* log2 */                            \
      s = __builtin_amdgcn_rcpf(c0);                                          \
    }                                                                         \
  }

#define GSTEP(j, APPLY, RENORM) GBODY(j, APPLY, RENORM)
#define TSTEP(j, APPLY, RENORM)                                               \
  if (tbase + (j) < nsteps) GBODY(j, APPLY, RENORM)

// per-group feat load: lane (= s*16+row) reads feats[b][tb+s][row], clamped.
#define LOADG(dst, tb)                                                        \
  { const int tcl = min((tb) + (lane >> 4), Ln - 1);                          \
    dst = fbase[(size_t)tcl * 16 + (lane & 15)]; }

// Kernel 1: wave (b,c) computes the transfer matrix of the EQUAL-WORK span
// [c*len/NC, (c+1)*len/NC):  T = prod_t diag(exp(feat_t)) * E,  E = exp(trans)
__global__ __launch_bounds__(256, 8) void crf_chunk(
    const float* __restrict__ feats, const int* __restrict__ mask,
    const int* __restrict__ tgt, const float* __restrict__ trans,
    const int* __restrict__ wsLen,
    float* __restrict__ wsT, float* __restrict__ wsLn, float* __restrict__ wsGold,
    int ncs)
{
  const int lane = threadIdx.x & 63;
  const int gwid = (blockIdx.x << 2) + (threadIdx.x >> 6);
  const int b = gwid >> ncs;
  const int c = gwid & ((1 << ncs) - 1);
  const int col = lane & 15;
  const int r0 = (lane >> 4) << 2;

  // A fragment: A[m=col][k=r0+i] = exp(trans[col][r0+i])
  s16x4 afrag;
  {
    const float4 tr = *(const float4*)(trans + col * 16 + r0);
    f32x4 e;
    e.x = __builtin_amdgcn_exp2f(tr.x * L2E);
    e.y = __builtin_amdgcn_exp2f(tr.y * L2E);
    e.z = __builtin_amdgcn_exp2f(tr.z * L2E);
    e.w = __builtin_amdgcn_exp2f(tr.w * L2E);
    afrag = pack_bf16(e);
  }

  const size_t bL = (size_t)b * Ln;
  const int len = wsLen[b];
  const int t0s = (c * len) >> ncs;
  const int t1s = ((c + 1) * len) >> ncs;
  const int nsteps = t1s - t0s;   // 64..256, never 0 (len >= Ln/2)

  f32x4 q;  // B = T (identity init). B[k=r0+i][n=col]; C/D layout == B layout.
  q.x = (r0 + 0 == col) ? 1.f : 0.f;
  q.y = (r0 + 1 == col) ? 1.f : 0.f;
  q.z = (r0 + 2 == col) ? 1.f : 0.f;
  q.w = (r0 + 3 == col) ? 1.f : 0.f;
  s16x4 bfrag = pack_bf16(q);
  float lnacc = 0.f, s = 1.f, pend = 0.f;
  const f32x4 zero = {0.f, 0.f, 0.f, 0.f};

  {
    const float* fbase = feats + bL * 16;
    // 2-stage pipeline: fv loaded 2 groups ahead, ex computed 1 group ahead.
    float fvN, exCur, exNext;
    { float fv0; LOADG(fv0, t0s); exCur = __builtin_amdgcn_exp2f(fv0 * L2E); }
    LOADG(fvN, t0s + 4);

    const int nfull = nsteps >> 2;
    const int tail = nsteps & 3;
    for (int g = 0; g < nfull; ++g) {
      exNext = __builtin_amdgcn_exp2f(fvN * L2E);
      LOADG(fvN, t0s + (g + 2) * 4);
      GSTEP(0, 1, 0) GSTEP(1, 0, 1) GSTEP(2, 1, 0) GSTEP(3, 0, 1)
      exCur = exNext;
    }
    if (tail) {
      const int tbase = nfull << 2;
      TSTEP(0, 1, 0) TSTEP(1, 0, 1) TSTEP(2, 1, 0)
    }
  }

  *(f32x4*)(wsT + ((size_t)gwid * 64 + lane) * 4) = q;
  if (lane == 0) wsLn[gwid] = lnacc;

  // ---- gold-path partial over the FIXED range [c*CHrt,(c+1)*CHrt) ----
  float gs = 0.f;
  const int CHrt = Ln >> ncs;
  const int tg0 = c * CHrt;
  const int ngold = CHrt >> 6;
  for (int k2 = 0; k2 < ngold; ++k2) {
    const int t = tg0 + k2 * 64 + lane;
    if (mask[bL + t]) {
      const int cur = tgt[bL + t];
      const int prv = (t == 0) ? 0 : tgt[bL + t - 1];  // START_TAG = 0
      gs += trans[cur * 16 + prv] + feats[(bL + t) * 16 + cur];
    }
  }
  for (int m = 1; m < 64; m <<= 1) gs += __shfl_xor(gs, m);
  if (lane == 0) atomicAdd(wsGold + b, gs);
}

// Kernel 2: per-batch wave combines chunk matrices against u0 = e_START,
// terminal logsumexp with trans[STOP] row, subtracts gold, reduces to scalar.
__global__ __launch_bounds__(256) void crf_combine(
    const int* __restrict__ tgt, const float* __restrict__ trans,
    const int* __restrict__ wsLen, const float* __restrict__ wsT,
    const float* __restrict__ wsLn, const float* __restrict__ wsGold,
    float* __restrict__ out, int ncs)
{
  const int lane = threadIdx.x & 63;
  const int b = (blockIdx.x << 2) + (threadIdx.x >> 6);
  const int col = lane & 15;
  const int NCrt = 1 << ncs;

  float u = (col == 0) ? 1.f : 0.f;  // exp(fv_init) = e_START
  float Lacc = 0.f;                  // log2 units

  for (int c = 0; c < NCrt; ++c) {
    const float4 tf = *(const float4*)(wsT + (((size_t)(b << ncs) + c) * 64 + lane) * 4);
    float p0 = tf.x * u, p1 = tf.y * u, p2 = tf.z * u, p3 = tf.w * u;
    for (int m = 1; m < 16; m <<= 1) {
      p0 += __shfl_xor(p0, m); p1 += __shfl_xor(p1, m);
      p2 += __shfl_xor(p2, m); p3 += __shfl_xor(p3, m);
    }
    const float pre = (lane & 2) ? ((lane & 1) ? p3 : p2) : ((lane & 1) ? p1 : p0);
    const int srcl = ((lane & 12) << 2) + (lane & 3);
    float un = __shfl(pre, srcl);
    const float c0 = fmaxf(rl0(un), 1e-30f);
    Lacc += __builtin_amdgcn_logf(c0) + wsLn[(size_t)(b << ncs) + c];
    u = un * __builtin_amdgcn_rcpf(c0);
  }

  float v = u * __builtin_amdgcn_exp2f(trans[16 + col] * L2E);  // STOP_TAG = 1
  for (int m = 1; m < 16; m <<= 1) v += __shfl_xor(v, m);
  v = fmaxf(v, 1e-30f);
  const float fwd = LN2 * (Lacc + __builtin_amdgcn_logf(v));

  if (lane == 0) {
    const size_t bL = (size_t)b * Ln;
    const int len = wsLen[b];
    const int last = tgt[bL + len - 1];
    const float gold = wsGold[b] + trans[16 + last];
    atomicAdd(out, (fwd - gold) * (1.f / 512.f));
  }
}

extern "C" void kernel_launch(void* const* d_in, const int* in_sizes, int n_in,
                              void* d_out, int out_size, void* d_ws, size_t ws_size,
                              hipStream_t stream) {
  const float* feats = (const float*)d_in[0];
  const int* mask = (const int*)d_in[1];
  const int* tgt = (const int*)d_in[2];
  const float* trans = (const float*)d_in[3];
  float* out = (float*)d_out;

  char* ws = (char*)d_ws;
  int*   wsLen  = (int*)ws;                        // 512 * 4B
  float* wsGold = (float*)(ws + 2048);             // 512 * 4B
  float* wsLn   = (float*)(ws + 4096);             // up to 16*512*4B = 32KB
  float* wsT    = (float*)(ws + 4096 + 32768);     // up to 16*512*256*4 = 8MB

  const size_t need16 = 4096 + 32768 + (size_t)16 * Bn * 256 * 4;
  const int ncs = (ws_size >= need16) ? 4 : 3;
  const int nwaves = Bn << ncs;

  hipMemsetAsync(d_out, 0, sizeof(float), stream);
  hipMemsetAsync(wsGold, 0, Bn * sizeof(float), stream);

  len_kernel<<<Bn / 4, 256, 0, stream>>>(mask, wsLen);
  crf_chunk<<<nwaves / 4, 256, 0, stream>>>(feats, mask, tgt, trans, wsLen,
                                            wsT, wsLn, wsGold, ncs);
  crf_combine<<<Bn / 4, 256, 0, stream>>>(tgt, trans, wsLen, wsT, wsLn, wsGold, out, ncs);
}